// Round 2
// baseline (1910.682 us; speedup 1.0000x reference)
//
#include <hip/hip_runtime.h>
#include <hip/hip_bf16.h>
#include <math.h>

#define B_ 4
#define S_ 2048
#define DM_ 2048
#define PROJ_STRIDE 320   // [k(64) | v(64) | q(64) | a(64) | w(64)]

// Full-wave (64-lane) sum via DPP row_shr/row_bcast, broadcast via readlane.
__device__ __forceinline__ float wave_reduce_add_f32(float x) {
  float t;
  t = __int_as_float(__builtin_amdgcn_update_dpp(0, __float_as_int(x), 0x111, 0xf, 0xf, true)); x += t; // row_shr:1
  t = __int_as_float(__builtin_amdgcn_update_dpp(0, __float_as_int(x), 0x112, 0xf, 0xf, true)); x += t; // row_shr:2
  t = __int_as_float(__builtin_amdgcn_update_dpp(0, __float_as_int(x), 0x114, 0xf, 0xf, true)); x += t; // row_shr:4
  t = __int_as_float(__builtin_amdgcn_update_dpp(0, __float_as_int(x), 0x118, 0xf, 0xf, true)); x += t; // row_shr:8
  t = __int_as_float(__builtin_amdgcn_update_dpp(0, __float_as_int(x), 0x142, 0xa, 0xf, true)); x += t; // row_bcast:15
  t = __int_as_float(__builtin_amdgcn_update_dpp(0, __float_as_int(x), 0x143, 0xc, 0xf, true)); x += t; // row_bcast:31
  return __int_as_float(__builtin_amdgcn_readlane(__float_as_int(x), 63));
}

// ---------------------------------------------------------------------------
// K1: fused projections. proj row (stride 320):
//   [0:64]=k(l2norm) [64:128]=v [128:192]=q(l2norm) [192:256]=alpha
//   [256:320]=w=(1-alpha)*k_norm  (precomputed for the scan's H-update)
// Block = 16 rows x 256 cols, 512 blocks, fp32 LDS-tiled GEMM.
// ---------------------------------------------------------------------------
__global__ __launch_bounds__(256) void k_proj(
    const float* __restrict__ x, const float* __restrict__ Wk,
    const float* __restrict__ Wv, const float* __restrict__ Wq,
    const float* __restrict__ Wa, const float* __restrict__ Wab,
    const float* __restrict__ lam, float* __restrict__ proj)
{
  __shared__ __align__(16) float xs[16 * 40];
  __shared__ __align__(16) float ws[32 * 260];
  const int tid = threadIdx.x;
  const int r0  = blockIdx.x * 16;
  const int ct  = tid & 63;
  const int rt  = tid >> 6;
  float acc[4][4];
  #pragma unroll
  for (int r = 0; r < 4; r++) { acc[r][0] = 0.f; acc[r][1] = 0.f; acc[r][2] = 0.f; acc[r][3] = 0.f; }

  const int sg = tid >> 3;
  const int sm = tid & 7;
  const float* wbase[4] = {Wk, Wv, Wq, Wa};

  for (int k0 = 0; k0 < DM_; k0 += 32) {
    if (tid < 128) {
      const int rr = tid >> 3;
      const int ko = (tid & 7) << 2;
      float4 xv = *(const float4*)(x + (size_t)(r0 + rr) * DM_ + k0 + ko);
      *(float4*)(xs + rr * 40 + ko) = xv;
    }
    #pragma unroll
    for (int p = 0; p < 8; p++) {
      const int c = sg + p * 32;
      const float* wb = wbase[p >> 1];
      const int cc = c - (p >> 1) * 64;
      float4 wv = *(const float4*)(wb + (size_t)cc * DM_ + k0 + sm * 4);
      ws[(sm * 4 + 0) * 260 + c] = wv.x;
      ws[(sm * 4 + 1) * 260 + c] = wv.y;
      ws[(sm * 4 + 2) * 260 + c] = wv.z;
      ws[(sm * 4 + 3) * 260 + c] = wv.w;
    }
    __syncthreads();
    #pragma unroll
    for (int kq = 0; kq < 8; kq++) {
      float4 xv[4];
      #pragma unroll
      for (int r = 0; r < 4; r++) xv[r] = *(const float4*)(xs + (rt * 4 + r) * 40 + kq * 4);
      #pragma unroll
      for (int i = 0; i < 4; i++) {
        const int kk = kq * 4 + i;
        float wv0 = ws[kk * 260 + ct];
        float wv1 = ws[kk * 260 + ct + 64];
        float wv2 = ws[kk * 260 + ct + 128];
        float wv3 = ws[kk * 260 + ct + 192];
        #pragma unroll
        for (int r = 0; r < 4; r++) {
          float xr = (i == 0) ? xv[r].x : (i == 1) ? xv[r].y : (i == 2) ? xv[r].z : xv[r].w;
          acc[r][0] = fmaf(xr, wv0, acc[r][0]);
          acc[r][1] = fmaf(xr, wv1, acc[r][1]);
          acc[r][2] = fmaf(xr, wv2, acc[r][2]);
          acc[r][3] = fmaf(xr, wv3, acc[r][3]);
        }
      }
    }
    __syncthreads();
  }
  float lamv = lam[ct];
  float la = logf(1.f / (1.f + expf(-lamv)) + 1e-8f);
  float bv = Wab[ct];
  #pragma unroll
  for (int r = 0; r < 4; r++) {
    float nk = wave_reduce_add_f32(acc[r][0] * acc[r][0]);
    float nq = wave_reduce_add_f32(acc[r][2] * acc[r][2]);
    nk = fmaxf(sqrtf(nk), 1e-12f);
    nq = fmaxf(sqrtf(nq), 1e-12f);
    float pre = acc[r][3] + bv;
    float rr_ = 1.f / (1.f + expf(-pre));
    float al  = expf(8.f * rr_ * la);
    float kn  = acc[r][0] / nk;
    float* pr = proj + (size_t)(r0 + rt * 4 + r) * PROJ_STRIDE;
    pr[ct]        = kn;
    pr[64 + ct]   = acc[r][1];
    pr[128 + ct]  = acc[r][2] / nq;
    pr[192 + ct]  = al;
    pr[256 + ct]  = (1.f - al) * kn;
  }
}

// ---------------------------------------------------------------------------
// K2: the sequential scan. 1 block/batch, 4 waves; wave w owns H rows
// [16w,16w+16), lane owns v-column. k/q/a/w slices loaded straight from
// global (wave-uniform -> broadcast, L2-resident), double-buffered one step
// ahead in registers. ONE LDS round-trip + raw lgkmcnt-only barrier per step
// (no vmcnt drain -> prefetch stays in flight). y written as 4 per-wave
// partials, summed in K3.
// ---------------------------------------------------------------------------
__device__ __forceinline__ void load_row(const float* __restrict__ r,
    float4 K[4], float4 Q[4], float4 A[4], float4 W[4], float& V,
    int w, int lane) {
  const float4* r4 = (const float4*)r;
  const int o = w * 4;             // this wave's 16-float slice, in quads
  #pragma unroll
  for (int i = 0; i < 4; i++) {
    K[i] = r4[o + i];              // k at float 0
    Q[i] = r4[32 + o + i];         // q at float 128
    A[i] = r4[48 + o + i];         // a at float 192
    W[i] = r4[64 + o + i];         // w at float 256
  }
  V = r[64 + lane];                // v at float 64, per-lane
}

__device__ __forceinline__ void scan_step(int t, const float* __restrict__ pb,
    float* __restrict__ yb, float H[16],
    float4 K[4], float4 Q[4], float4 A[4], float4 W[4], float& V,
    float (*sp)[4], float (*sk)[4], int w, int lane) {
  // pred/kH partials over this wave's 16 rows (2 accumulators each)
  float pA = 0.f, pB = 0.f, kA = 0.f, kB = 0.f;
  #pragma unroll
  for (int jq = 0; jq < 4; jq++) {
    pA = fmaf(Q[jq].x, H[4 * jq + 0], pA); kA = fmaf(K[jq].x, H[4 * jq + 0], kA);
    pB = fmaf(Q[jq].y, H[4 * jq + 1], pB); kB = fmaf(K[jq].y, H[4 * jq + 1], kB);
    pA = fmaf(Q[jq].z, H[4 * jq + 2], pA); kA = fmaf(K[jq].z, H[4 * jq + 2], kA);
    pB = fmaf(Q[jq].w, H[4 * jq + 3], pB); kB = fmaf(K[jq].w, H[4 * jq + 3], kB);
  }
  sp[lane][w] = pA + pB;
  sk[lane][w] = kA + kB;
  // LDS-only barrier: do NOT drain vmcnt (keeps prefetch + y-stores in flight)
  asm volatile("s_waitcnt lgkmcnt(0)\n\ts_barrier" ::: "memory");
  float4 P  = *(const float4*)sp[lane];   // conflict-free b128
  float4 Kp = *(const float4*)sk[lane];
  float pred = (P.x + P.y) + (P.z + P.w);
  float kh   = (Kp.x + Kp.y) + (Kp.z + Kp.w);
  float d = V - pred;
  float e = wave_reduce_add_f32(d * d);
  float s = __builtin_amdgcn_rcpf(1.f + __expf(-e * (1.f / 1.000001f)));
  float g = s * (V - kh);
  // H-update + y partial (w = (1-a)*k_norm precomputed in k_proj)
  float yA = 0.f, yB = 0.f;
  #pragma unroll
  for (int jq = 0; jq < 4; jq++) {
    H[4 * jq + 0] = fmaf(A[jq].x, H[4 * jq + 0], W[jq].x * g); yA = fmaf(Q[jq].x, H[4 * jq + 0], yA);
    H[4 * jq + 1] = fmaf(A[jq].y, H[4 * jq + 1], W[jq].y * g); yB = fmaf(Q[jq].y, H[4 * jq + 1], yB);
    H[4 * jq + 2] = fmaf(A[jq].z, H[4 * jq + 2], W[jq].z * g); yA = fmaf(Q[jq].z, H[4 * jq + 2], yA);
    H[4 * jq + 3] = fmaf(A[jq].w, H[4 * jq + 3], W[jq].w * g); yB = fmaf(Q[jq].w, H[4 * jq + 3], yB);
  }
  yb[(size_t)t * 256 + w * 64 + lane] = yA + yB;
  // prefetch step t+2 into the registers this step just consumed
  const int tp = t + 2;
  if (tp < S_) load_row(pb + (size_t)tp * PROJ_STRIDE, K, Q, A, W, V, w, lane);
}

__global__ __launch_bounds__(256) void k_scan(const float* __restrict__ proj,
                                              float* __restrict__ ypart)
{
  __shared__ __align__(16) float sp0[64][4], sk0[64][4], sp1[64][4], sk1[64][4];
  const int b    = blockIdx.x;
  const int tid  = threadIdx.x;
  const int w    = tid >> 6;
  const int lane = tid & 63;
  const float* pb = proj + (size_t)b * S_ * PROJ_STRIDE;
  float* yb = ypart + (size_t)b * S_ * 256;
  float H[16];
  #pragma unroll
  for (int j = 0; j < 16; j++) H[j] = 0.f;
  float4 KA[4], QA[4], AA[4], WA[4]; float VA;
  float4 KB[4], QB[4], AB[4], WB[4]; float VB;
  load_row(pb,               KA, QA, AA, WA, VA, w, lane);
  load_row(pb + PROJ_STRIDE, KB, QB, AB, WB, VB, w, lane);
  for (int t = 0; t < S_; t += 2) {
    scan_step(t,     pb, yb, H, KA, QA, AA, WA, VA, sp0, sk0, w, lane);
    scan_step(t + 1, pb, yb, H, KB, QB, AB, WB, VB, sp1, sk1, w, lane);
  }
}

// ---------------------------------------------------------------------------
// Wo transpose (2048x64 -> 64x2048) so K3's inner loop reads coalesced.
// ---------------------------------------------------------------------------
__global__ __launch_bounds__(256) void k_trans(const float* __restrict__ Wo,
                                               float* __restrict__ WoT) {
  int i = blockIdx.x * 256 + threadIdx.x;
  int d = i >> 11;
  int c = i & 2047;
  WoT[i] = Wo[(size_t)c * 64 + d];
}

// ---------------------------------------------------------------------------
// K3: sum y-partials, RMS-norm over 64, * norm_w, then yn @ Wo^T.
// ---------------------------------------------------------------------------
__global__ __launch_bounds__(256) void k_out(const float* __restrict__ ypart,
    const float* __restrict__ norm_w, const float* __restrict__ WoT,
    float* __restrict__ out)
{
  __shared__ __align__(16) float yn[16 * 64];
  const int tid = threadIdx.x;
  const int r0  = blockIdx.x * 16;
  const int c0  = blockIdx.y * 512;
  {
    const int r = tid >> 4;
    const int d = (tid & 15) * 4;
    const float* yp = ypart + (size_t)(r0 + r) * 256;
    float4 y0 = *(const float4*)(yp + d);
    float4 y1 = *(const float4*)(yp + 64 + d);
    float4 y2 = *(const float4*)(yp + 128 + d);
    float4 y3 = *(const float4*)(yp + 192 + d);
    float yx = y0.x + y1.x + y2.x + y3.x;
    float yy = y0.y + y1.y + y2.y + y3.y;
    float yz = y0.z + y1.z + y2.z + y3.z;
    float yw = y0.w + y1.w + y2.w + y3.w;
    float sq = yx * yx + yy * yy + yz * yz + yw * yw;
    sq += __shfl_xor(sq, 1, 64);
    sq += __shfl_xor(sq, 2, 64);
    sq += __shfl_xor(sq, 4, 64);
    sq += __shfl_xor(sq, 8, 64);
    float rms = rsqrtf(sq * (1.f / 64.f) + 1e-6f);
    float4 nw = *(const float4*)(norm_w + d);
    yn[r * 64 + d + 0] = yx * rms * nw.x;
    yn[r * 64 + d + 1] = yy * rms * nw.y;
    yn[r * 64 + d + 2] = yz * rms * nw.z;
    yn[r * 64 + d + 3] = yw * rms * nw.w;
  }
  __syncthreads();
  const int ctq = tid & 127;
  const int rt  = tid >> 7;
  float acc[8][4];
  #pragma unroll
  for (int r = 0; r < 8; r++) { acc[r][0] = 0.f; acc[r][1] = 0.f; acc[r][2] = 0.f; acc[r][3] = 0.f; }
  #pragma unroll 8
  for (int d = 0; d < 64; d++) {
    float4 wv = *(const float4*)(WoT + (size_t)d * 2048 + c0 + ctq * 4);
    #pragma unroll
    for (int r = 0; r < 8; r++) {
      float yv = yn[(rt * 8 + r) * 64 + d];
      acc[r][0] = fmaf(yv, wv.x, acc[r][0]);
      acc[r][1] = fmaf(yv, wv.y, acc[r][1]);
      acc[r][2] = fmaf(yv, wv.z, acc[r][2]);
      acc[r][3] = fmaf(yv, wv.w, acc[r][3]);
    }
  }
  #pragma unroll
  for (int r = 0; r < 8; r++) {
    float4 o; o.x = acc[r][0]; o.y = acc[r][1]; o.z = acc[r][2]; o.w = acc[r][3];
    *(float4*)(out + (size_t)(r0 + rt * 8 + r) * 2048 + c0 + ctq * 4) = o;
  }
}

extern "C" void kernel_launch(void* const* d_in, const int* in_sizes, int n_in,
                              void* d_out, int out_size, void* d_ws, size_t ws_size,
                              hipStream_t stream) {
  const float* x   = (const float*)d_in[0];
  const float* Wk  = (const float*)d_in[1];
  const float* Wv  = (const float*)d_in[2];
  const float* Wq  = (const float*)d_in[3];
  const float* Wa  = (const float*)d_in[4];
  const float* Wab = (const float*)d_in[5];
  const float* lam = (const float*)d_in[6];
  const float* nw  = (const float*)d_in[7];
  const float* Wo  = (const float*)d_in[8];
  float* out = (float*)d_out;

  float* wsf   = (float*)d_ws;
  float* proj  = wsf;                 // B*S*320 = 2,621,440 floats
  float* ypart = wsf + 2621440;       // B*S*256 = 2,097,152 floats
  float* WoT   = wsf + 4718592;       // 64*2048 = 131,072 floats

  k_trans<<<dim3(512), dim3(256), 0, stream>>>(Wo, WoT);
  k_proj <<<dim3(512), dim3(256), 0, stream>>>(x, Wk, Wv, Wq, Wa, Wab, lam, proj);
  k_scan <<<dim3(4),   dim3(256), 0, stream>>>(proj, ypart);
  k_out  <<<dim3(512, 4), dim3(256), 0, stream>>>(ypart, nw, WoT, out);
}

// Round 4
// 1717.178 us; speedup vs baseline: 1.1127x; 1.1127x over previous
//
#include <hip/hip_runtime.h>
#include <hip/hip_bf16.h>
#include <math.h>

#define B_ 4
#define S_ 2048
#define DM_ 2048
#define PST 416        // proj row stride (floats): k@0 | v@64 | q@128 | a@192 | w@256 | qa@320 | qw@384 | pad
#define PST4 104       // row stride in float4

// Full-wave (64-lane) sum via DPP row_shr/row_bcast, broadcast via readlane.
__device__ __forceinline__ float wave_reduce_add_f32(float x) {
  float t;
  t = __int_as_float(__builtin_amdgcn_update_dpp(0, __float_as_int(x), 0x111, 0xf, 0xf, true)); x += t;
  t = __int_as_float(__builtin_amdgcn_update_dpp(0, __float_as_int(x), 0x112, 0xf, 0xf, true)); x += t;
  t = __int_as_float(__builtin_amdgcn_update_dpp(0, __float_as_int(x), 0x114, 0xf, 0xf, true)); x += t;
  t = __int_as_float(__builtin_amdgcn_update_dpp(0, __float_as_int(x), 0x118, 0xf, 0xf, true)); x += t;
  t = __int_as_float(__builtin_amdgcn_update_dpp(0, __float_as_int(x), 0x142, 0xa, 0xf, true)); x += t;
  t = __int_as_float(__builtin_amdgcn_update_dpp(0, __float_as_int(x), 0x143, 0xc, 0xf, true)); x += t;
  return __int_as_float(__builtin_amdgcn_readlane(__float_as_int(x), 63));
}

// ---------------------------------------------------------------------------
// K1: fused projections + scan-precompute epilogue.
// ---------------------------------------------------------------------------
__global__ __launch_bounds__(256) void k_proj(
    const float* __restrict__ x, const float* __restrict__ Wk,
    const float* __restrict__ Wv, const float* __restrict__ Wq,
    const float* __restrict__ Wa, const float* __restrict__ Wab,
    const float* __restrict__ lam, float* __restrict__ proj)
{
  __shared__ __align__(16) float xs[16 * 40];
  __shared__ __align__(16) float ws[32 * 260];
  const int tid = threadIdx.x;
  const int r0  = blockIdx.x * 16;
  const int ct  = tid & 63;
  const int rt  = tid >> 6;
  float acc[4][4];
  #pragma unroll
  for (int r = 0; r < 4; r++) { acc[r][0] = 0.f; acc[r][1] = 0.f; acc[r][2] = 0.f; acc[r][3] = 0.f; }

  const int sg = tid >> 3;
  const int sm = tid & 7;
  const float* wbase[4] = {Wk, Wv, Wq, Wa};

  for (int k0 = 0; k0 < DM_; k0 += 32) {
    if (tid < 128) {
      const int rr = tid >> 3;
      const int ko = (tid & 7) << 2;
      float4 xv = *(const float4*)(x + (size_t)(r0 + rr) * DM_ + k0 + ko);
      *(float4*)(xs + rr * 40 + ko) = xv;
    }
    #pragma unroll
    for (int p = 0; p < 8; p++) {
      const int c = sg + p * 32;
      const float* wb = wbase[p >> 1];
      const int cc = c - (p >> 1) * 64;
      float4 wv = *(const float4*)(wb + (size_t)cc * DM_ + k0 + sm * 4);
      ws[(sm * 4 + 0) * 260 + c] = wv.x;
      ws[(sm * 4 + 1) * 260 + c] = wv.y;
      ws[(sm * 4 + 2) * 260 + c] = wv.z;
      ws[(sm * 4 + 3) * 260 + c] = wv.w;
    }
    __syncthreads();
    #pragma unroll
    for (int kq = 0; kq < 8; kq++) {
      float4 xv[4];
      #pragma unroll
      for (int r = 0; r < 4; r++) xv[r] = *(const float4*)(xs + (rt * 4 + r) * 40 + kq * 4);
      #pragma unroll
      for (int i = 0; i < 4; i++) {
        const int kk = kq * 4 + i;
        float wv0 = ws[kk * 260 + ct];
        float wv1 = ws[kk * 260 + ct + 64];
        float wv2 = ws[kk * 260 + ct + 128];
        float wv3 = ws[kk * 260 + ct + 192];
        #pragma unroll
        for (int r = 0; r < 4; r++) {
          float xr = (i == 0) ? xv[r].x : (i == 1) ? xv[r].y : (i == 2) ? xv[r].z : xv[r].w;
          acc[r][0] = fmaf(xr, wv0, acc[r][0]);
          acc[r][1] = fmaf(xr, wv1, acc[r][1]);
          acc[r][2] = fmaf(xr, wv2, acc[r][2]);
          acc[r][3] = fmaf(xr, wv3, acc[r][3]);
        }
      }
    }
    __syncthreads();
  }
  float lamv = lam[ct];
  float la = logf(1.f / (1.f + expf(-lamv)) + 1e-8f);
  float bv = Wab[ct];
  #pragma unroll
  for (int r = 0; r < 4; r++) {
    float nk = wave_reduce_add_f32(acc[r][0] * acc[r][0]);
    float nq = wave_reduce_add_f32(acc[r][2] * acc[r][2]);
    nk = fmaxf(sqrtf(nk), 1e-12f);
    nq = fmaxf(sqrtf(nq), 1e-12f);
    float pre = acc[r][3] + bv;
    float rr_ = 1.f / (1.f + expf(-pre));
    float al  = expf(8.f * rr_ * la);
    float kn  = acc[r][0] / nk;
    float qn  = acc[r][2] / nq;
    float w_  = (1.f - al) * kn;          // (1-alpha)*k_norm
    float qa_ = qn * al;                  // q*alpha
    float qw  = wave_reduce_add_f32(qn * w_);  // scalar q.w per row
    float* pr = proj + (size_t)(r0 + rt * 4 + r) * PST;
    pr[ct]        = kn;
    pr[64 + ct]   = acc[r][1];
    pr[128 + ct]  = qn;
    pr[192 + ct]  = al;
    pr[256 + ct]  = w_;
    pr[320 + ct]  = qa_;
    if (ct == 0) pr[384] = qw;
  }
}

// ---------------------------------------------------------------------------
// K2: sequential scan. 1 block/batch, 4 waves x 16 H-rows, lane = v-column.
// Inputs staged through a 16-slot LDS ring, burst-refilled every 8 steps with
// loads issued 16 steps ahead (held 8 steps in registers -> latency fully
// hidden). Per-step: one conflict-free float2 LDS exchange + lgkm-only
// barrier. y computed from H_old via qa/qw trick (off the serial tail).
// ---------------------------------------------------------------------------
struct InSet { float4 K[4], Q[4], QA[4]; float V; };

__device__ __forceinline__ void prefetch_in(const float* __restrict__ slot,
                                            InSet& s, int w, int lane) {
  const float4* s4 = (const float4*)slot;
  const int o = w * 4;
  #pragma unroll
  for (int i = 0; i < 4; i++) {
    s.K[i]  = s4[o + i];        // k  @ f4 idx 0
    s.Q[i]  = s4[32 + o + i];   // q  @ 128 floats
    s.QA[i] = s4[80 + o + i];   // qa @ 320 floats
  }
  s.V = slot[64 + lane];        // v  @ 64 floats, per-lane
}

__device__ __forceinline__ void refill(int t, float* __restrict__ ring,
    float4 P[4], const float4* __restrict__ pb4, int tid) {
  // write pending burst (steps [t+8,t+16)) into its ring half
  float4* dst = (float4*)(ring + ((t + 8) & 8) * PST);
  dst[tid] = P[0]; dst[tid + 256] = P[1]; dst[tid + 512] = P[2];
  if (tid < 64) dst[tid + 768] = P[3];
  // issue loads for steps [t+16,t+24) (clamped at the end of the sequence)
  const int lim = S_ * PST4 - 1;
  const int base = (t + 16) * PST4;
  P[0] = pb4[min(base + tid,       lim)];
  P[1] = pb4[min(base + tid + 256, lim)];
  P[2] = pb4[min(base + tid + 512, lim)];
  if (tid < 64) P[3] = pb4[min(base + tid + 768, lim)];
}

__device__ __forceinline__ void scan_step(int t, const float* __restrict__ ring,
    float2* __restrict__ xchp, float* __restrict__ yb, float H[16],
    InSet& cur, InSet& nxt, int w, int lane, float qwSel)
{
  const float* slotc = ring + (t & 15) * PST;
  const float* slotn = ring + ((t + 1) & 15) * PST;
  // (0) issue all LDS reads for this step + next-step inputs (latency hidden
  //     behind phase-1 FMAs; completed by the lgkmcnt(0) at the barrier)
  float4 Av[4], Wv[4];
  {
    const float4* sc4 = (const float4*)slotc;
    const int o = w * 4;
    #pragma unroll
    for (int i = 0; i < 4; i++) { Av[i] = sc4[48 + o + i]; Wv[i] = sc4[64 + o + i]; }
  }
  float qw = slotc[384];
  prefetch_in(slotn, nxt, w, lane);
  // (1) three dots over this wave's 16 rows of H_old: pred(q), kH(k), y(qa)
  float pA = 0.f, pB = 0.f, kA = 0.f, kB = 0.f, yA = 0.f, yB = 0.f;
  #pragma unroll
  for (int j = 0; j < 4; j++) {
    pA = fmaf(cur.Q[j].x, H[4*j+0], pA); kA = fmaf(cur.K[j].x, H[4*j+0], kA); yA = fmaf(cur.QA[j].x, H[4*j+0], yA);
    pB = fmaf(cur.Q[j].y, H[4*j+1], pB); kB = fmaf(cur.K[j].y, H[4*j+1], kB); yB = fmaf(cur.QA[j].y, H[4*j+1], yB);
    pA = fmaf(cur.Q[j].z, H[4*j+2], pA); kA = fmaf(cur.K[j].z, H[4*j+2], kA); yA = fmaf(cur.QA[j].z, H[4*j+2], yA);
    pB = fmaf(cur.Q[j].w, H[4*j+3], pB); kB = fmaf(cur.K[j].w, H[4*j+3], kB); yB = fmaf(cur.QA[j].w, H[4*j+3], yB);
  }
  // (2) exchange: [w][lane] float2 -> 2-dword lane stride, conflict-free
  xchp[w * 64 + lane] = make_float2(pA + pB, kA + kB);
  // (3) LDS-only barrier (no vmcnt drain)
  asm volatile("s_waitcnt lgkmcnt(0)\n\ts_barrier" ::: "memory");
  // (4) cross-wave sums
  float2 x0 = xchp[lane], x1 = xchp[64 + lane], x2 = xchp[128 + lane], x3 = xchp[192 + lane];
  float pred = (x0.x + x1.x) + (x2.x + x3.x);
  float kh   = (x0.y + x1.y) + (x2.y + x3.y);
  // (5) surprise gate
  float d = cur.V - pred;
  float e = wave_reduce_add_f32(d * d);
  float s = __builtin_amdgcn_rcpf(1.f + __builtin_amdgcn_exp2f(e * -1.4426936f)); // sigmoid(e/1.000001)
  float g = s * (cur.V - kh);
  // (6) y from H_old (qa.H partial) + qw*g (wave 0 only); fire-and-forget
  yb[(size_t)t * 256 + w * 64 + lane] = (yA + yB) + qwSel * (qw * g);
  // (7) H update: H = a*H + w*g
  #pragma unroll
  for (int j = 0; j < 4; j++) {
    H[4*j+0] = fmaf(Av[j].x, H[4*j+0], Wv[j].x * g);
    H[4*j+1] = fmaf(Av[j].y, H[4*j+1], Wv[j].y * g);
    H[4*j+2] = fmaf(Av[j].z, H[4*j+2], Wv[j].z * g);
    H[4*j+3] = fmaf(Av[j].w, H[4*j+3], Wv[j].w * g);
  }
}

__global__ __launch_bounds__(256, 1) void k_scan(const float* __restrict__ proj,
                                                 float* __restrict__ ypart)
{
  __shared__ __align__(16) float ring[16 * PST];   // 26.6 KB
  __shared__ __align__(16) float2 xch[2][4 * 64];  // 4 KB, double-buffered
  const int b = blockIdx.x, tid = threadIdx.x;
  const int w = tid >> 6, lane = tid & 63;
  const float* pb = proj + (size_t)b * S_ * PST;
  const float4* pb4 = (const float4*)pb;
  float* yb = ypart + (size_t)b * S_ * 256;
  float H[16];
  #pragma unroll
  for (int j = 0; j < 16; j++) H[j] = 0.f;
  // init: fill slots [0,8); load pending burst [8,16)
  float4 P[4];
  P[0] = pb4[tid]; P[1] = pb4[tid + 256]; P[2] = pb4[tid + 512];
  if (tid < 64) P[3] = pb4[tid + 768];
  {
    float4* dst = (float4*)ring;
    dst[tid] = P[0]; dst[tid + 256] = P[1]; dst[tid + 512] = P[2];
    if (tid < 64) dst[tid + 768] = P[3];
  }
  {
    const int base = 8 * PST4;
    P[0] = pb4[base + tid]; P[1] = pb4[base + tid + 256]; P[2] = pb4[base + tid + 512];
    if (tid < 64) P[3] = pb4[base + tid + 768];
  }
  __syncthreads();
  const float qwSel = (w == 0) ? 1.f : 0.f;
  InSet inA, inB;
  prefetch_in(ring, inA, w, lane);   // step-0 inputs (slot 0)
  for (int t = 0; t < S_; t += 2) {
    if ((t & 7) == 0) refill(t, ring, P, pb4, tid);
    scan_step(t,     ring, xch[0], yb, H, inA, inB, w, lane, qwSel);
    scan_step(t + 1, ring, xch[1], yb, H, inB, inA, w, lane, qwSel);
  }
}

// ---------------------------------------------------------------------------
// Wo transpose (2048x64 -> 64x2048).
// ---------------------------------------------------------------------------
__global__ __launch_bounds__(256) void k_trans(const float* __restrict__ Wo,
                                               float* __restrict__ WoT) {
  int i = blockIdx.x * 256 + threadIdx.x;
  int d = i >> 11;
  int c = i & 2047;
  WoT[i] = Wo[(size_t)c * 64 + d];
}

// ---------------------------------------------------------------------------
// K3: sum y-partials, RMS-norm over 64, * norm_w, then yn @ Wo^T.
// ---------------------------------------------------------------------------
__global__ __launch_bounds__(256) void k_out(const float* __restrict__ ypart,
    const float* __restrict__ norm_w, const float* __restrict__ WoT,
    float* __restrict__ out)
{
  __shared__ __align__(16) float yn[16 * 64];
  const int tid = threadIdx.x;
  const int r0  = blockIdx.x * 16;
  const int c0  = blockIdx.y * 512;
  {
    const int r = tid >> 4;
    const int d = (tid & 15) * 4;
    const float* yp = ypart + (size_t)(r0 + r) * 256;
    float4 y0 = *(const float4*)(yp + d);
    float4 y1 = *(const float4*)(yp + 64 + d);
    float4 y2 = *(const float4*)(yp + 128 + d);
    float4 y3 = *(const float4*)(yp + 192 + d);
    float yx = y0.x + y1.x + y2.x + y3.x;
    float yy = y0.y + y1.y + y2.y + y3.y;
    float yz = y0.z + y1.z + y2.z + y3.z;
    float yw = y0.w + y1.w + y2.w + y3.w;
    float sq = yx * yx + yy * yy + yz * yz + yw * yw;
    sq += __shfl_xor(sq, 1, 64);
    sq += __shfl_xor(sq, 2, 64);
    sq += __shfl_xor(sq, 4, 64);
    sq += __shfl_xor(sq, 8, 64);
    float rms = rsqrtf(sq * (1.f / 64.f) + 1e-6f);
    float4 nw = *(const float4*)(norm_w + d);
    yn[r * 64 + d + 0] = yx * rms * nw.x;
    yn[r * 64 + d + 1] = yy * rms * nw.y;
    yn[r * 64 + d + 2] = yz * rms * nw.z;
    yn[r * 64 + d + 3] = yw * rms * nw.w;
  }
  __syncthreads();
  const int ctq = tid & 127;
  const int rt  = tid >> 7;
  float acc[8][4];
  #pragma unroll
  for (int r = 0; r < 8; r++) { acc[r][0] = 0.f; acc[r][1] = 0.f; acc[r][2] = 0.f; acc[r][3] = 0.f; }
  #pragma unroll 8
  for (int d = 0; d < 64; d++) {
    float4 wv = *(const float4*)(WoT + (size_t)d * 2048 + c0 + ctq * 4);
    #pragma unroll
    for (int r = 0; r < 8; r++) {
      float yv = yn[(rt * 8 + r) * 64 + d];
      acc[r][0] = fmaf(yv, wv.x, acc[r][0]);
      acc[r][1] = fmaf(yv, wv.y, acc[r][1]);
      acc[r][2] = fmaf(yv, wv.z, acc[r][2]);
      acc[r][3] = fmaf(yv, wv.w, acc[r][3]);
    }
  }
  #pragma unroll
  for (int r = 0; r < 8; r++) {
    float4 o; o.x = acc[r][0]; o.y = acc[r][1]; o.z = acc[r][2]; o.w = acc[r][3];
    *(float4*)(out + (size_t)(r0 + rt * 8 + r) * 2048 + c0 + ctq * 4) = o;
  }
}

extern "C" void kernel_launch(void* const* d_in, const int* in_sizes, int n_in,
                              void* d_out, int out_size, void* d_ws, size_t ws_size,
                              hipStream_t stream) {
  const float* x   = (const float*)d_in[0];
  const float* Wk  = (const float*)d_in[1];
  const float* Wv  = (const float*)d_in[2];
  const float* Wq  = (const float*)d_in[3];
  const float* Wa  = (const float*)d_in[4];
  const float* Wab = (const float*)d_in[5];
  const float* lam = (const float*)d_in[6];
  const float* nw  = (const float*)d_in[7];
  const float* Wo  = (const float*)d_in[8];
  float* out = (float*)d_out;

  float* wsf   = (float*)d_ws;
  float* proj  = wsf;                 // B*S*416 = 3,407,872 floats
  float* ypart = wsf + 3407872;       // B*S*256 = 2,097,152 floats
  float* WoT   = wsf + 5505024;       // 64*2048 = 131,072 floats

  k_trans<<<dim3(512), dim3(256), 0, stream>>>(Wo, WoT);
  k_proj <<<dim3(512), dim3(256), 0, stream>>>(x, Wk, Wv, Wq, Wa, Wab, lam, proj);
  k_scan <<<dim3(4),   dim3(256), 0, stream>>>(proj, ypart);
  k_out  <<<dim3(512, 4), dim3(256), 0, stream>>>(ypart, nw, WoT, out);
}

// Round 5
// 1717.075 us; speedup vs baseline: 1.1128x; 1.0001x over previous
//
#include <hip/hip_runtime.h>
#include <hip/hip_bf16.h>
#include <math.h>

#define S_ 2048
#define DM_ 2048
#define PST 320        // proj row stride (floats): k@0 | v@64 | q@128 | a@192 | w@256

// Full-wave (64-lane) sum via DPP row_shr/row_bcast, broadcast via readlane.
__device__ __forceinline__ float wave_reduce_add_f32(float x) {
  float t;
  t = __int_as_float(__builtin_amdgcn_update_dpp(0, __float_as_int(x), 0x111, 0xf, 0xf, true)); x += t;
  t = __int_as_float(__builtin_amdgcn_update_dpp(0, __float_as_int(x), 0x112, 0xf, 0xf, true)); x += t;
  t = __int_as_float(__builtin_amdgcn_update_dpp(0, __float_as_int(x), 0x114, 0xf, 0xf, true)); x += t;
  t = __int_as_float(__builtin_amdgcn_update_dpp(0, __float_as_int(x), 0x118, 0xf, 0xf, true)); x += t;
  t = __int_as_float(__builtin_amdgcn_update_dpp(0, __float_as_int(x), 0x142, 0xa, 0xf, true)); x += t;
  t = __int_as_float(__builtin_amdgcn_update_dpp(0, __float_as_int(x), 0x143, 0xc, 0xf, true)); x += t;
  return __int_as_float(__builtin_amdgcn_readlane(__float_as_int(x), 63));
}

// ---------------------------------------------------------------------------
// K1: fused projections. proj row (stride 320):
//   k(l2norm)@0 | v@64 | q(l2norm)@128 | alpha@192 | w=(1-alpha)*k_norm@256
// ---------------------------------------------------------------------------
__global__ __launch_bounds__(256) void k_proj(
    const float* __restrict__ x, const float* __restrict__ Wk,
    const float* __restrict__ Wv, const float* __restrict__ Wq,
    const float* __restrict__ Wa, const float* __restrict__ Wab,
    const float* __restrict__ lam, float* __restrict__ proj)
{
  __shared__ __align__(16) float xs[16 * 40];
  __shared__ __align__(16) float ws[32 * 260];
  const int tid = threadIdx.x;
  const int r0  = blockIdx.x * 16;
  const int ct  = tid & 63;
  const int rt  = tid >> 6;
  float acc[4][4];
  #pragma unroll
  for (int r = 0; r < 4; r++) { acc[r][0] = 0.f; acc[r][1] = 0.f; acc[r][2] = 0.f; acc[r][3] = 0.f; }

  const int sg = tid >> 3;
  const int sm = tid & 7;
  const float* wbase[4] = {Wk, Wv, Wq, Wa};

  for (int k0 = 0; k0 < DM_; k0 += 32) {
    if (tid < 128) {
      const int rr = tid >> 3;
      const int ko = (tid & 7) << 2;
      float4 xv = *(const float4*)(x + (size_t)(r0 + rr) * DM_ + k0 + ko);
      *(float4*)(xs + rr * 40 + ko) = xv;
    }
    #pragma unroll
    for (int p = 0; p < 8; p++) {
      const int c = sg + p * 32;
      const float* wb = wbase[p >> 1];
      const int cc = c - (p >> 1) * 64;
      float4 wv = *(const float4*)(wb + (size_t)cc * DM_ + k0 + sm * 4);
      ws[(sm * 4 + 0) * 260 + c] = wv.x;
      ws[(sm * 4 + 1) * 260 + c] = wv.y;
      ws[(sm * 4 + 2) * 260 + c] = wv.z;
      ws[(sm * 4 + 3) * 260 + c] = wv.w;
    }
    __syncthreads();
    #pragma unroll
    for (int kq = 0; kq < 8; kq++) {
      float4 xv[4];
      #pragma unroll
      for (int r = 0; r < 4; r++) xv[r] = *(const float4*)(xs + (rt * 4 + r) * 40 + kq * 4);
      #pragma unroll
      for (int i = 0; i < 4; i++) {
        const int kk = kq * 4 + i;
        float wv0 = ws[kk * 260 + ct];
        float wv1 = ws[kk * 260 + ct + 64];
        float wv2 = ws[kk * 260 + ct + 128];
        float wv3 = ws[kk * 260 + ct + 192];
        #pragma unroll
        for (int r = 0; r < 4; r++) {
          float xr = (i == 0) ? xv[r].x : (i == 1) ? xv[r].y : (i == 2) ? xv[r].z : xv[r].w;
          acc[r][0] = fmaf(xr, wv0, acc[r][0]);
          acc[r][1] = fmaf(xr, wv1, acc[r][1]);
          acc[r][2] = fmaf(xr, wv2, acc[r][2]);
          acc[r][3] = fmaf(xr, wv3, acc[r][3]);
        }
      }
    }
    __syncthreads();
  }
  float lamv = lam[ct];
  float la = logf(1.f / (1.f + expf(-lamv)) + 1e-8f);
  float bv = Wab[ct];
  #pragma unroll
  for (int r = 0; r < 4; r++) {
    float nk = wave_reduce_add_f32(acc[r][0] * acc[r][0]);
    float nq = wave_reduce_add_f32(acc[r][2] * acc[r][2]);
    nk = fmaxf(sqrtf(nk), 1e-12f);
    nq = fmaxf(sqrtf(nq), 1e-12f);
    float pre = acc[r][3] + bv;
    float rr_ = 1.f / (1.f + expf(-pre));
    float al  = expf(8.f * rr_ * la);
    float kn  = acc[r][0] / nk;
    float qn  = acc[r][2] / nq;
    float* pr = proj + (size_t)(r0 + rt * 4 + r) * PST;
    pr[ct]        = kn;
    pr[64 + ct]   = acc[r][1];
    pr[128 + ct]  = qn;
    pr[192 + ct]  = al;
    pr[256 + ct]  = (1.f - al) * kn;
  }
}

// ---------------------------------------------------------------------------
// K2: sequential scan. 1 block/batch, 4 waves; wave w owns H rows
// [16w,16w+16), lane = v-column. ALL inputs arrive as VGPR-uniform global
// broadcast loads (zero LDS pipe), 4-slot register pipeline issued 3 steps
// ahead (covers far-L2/HBM miss latency). Per-step LDS = one 8-byte
// exchange write + 4 reads + lgkm-only barrier. aH precomputed pre-barrier.
// ---------------------------------------------------------------------------
__device__ __forceinline__ void ld_slot(const float* __restrict__ pb, int t,
    int w, int lane, float4 K[4], float4 Q[4], float4 A[4], float4 W[4],
    float& V) {
  const float* r = pb + (size_t)t * PST + (w << 4);
  #pragma unroll
  for (int i = 0; i < 4; i++) {
    K[i] = *(const float4*)(r + 4 * i);          // k slice  (wave-uniform)
    Q[i] = *(const float4*)(r + 128 + 4 * i);    // q slice
    A[i] = *(const float4*)(r + 192 + 4 * i);    // a slice
    W[i] = *(const float4*)(r + 256 + 4 * i);    // w slice
  }
  V = pb[(size_t)t * PST + 64 + lane];           // v, per-lane
}

__device__ __forceinline__ void sstep(int t, float2* __restrict__ buf,
    float* __restrict__ yb, float H[16],
    const float4 K[4], const float4 Q[4], const float4 A[4], const float4 W[4],
    float V, int w, int lane)
{
  // (1) pred/kH partials over this wave's 16 rows of H_old
  float pA = 0.f, pB = 0.f, kA = 0.f, kB = 0.f;
  #pragma unroll
  for (int j = 0; j < 4; j++) {
    pA = fmaf(Q[j].x, H[4*j+0], pA); kA = fmaf(K[j].x, H[4*j+0], kA);
    pB = fmaf(Q[j].y, H[4*j+1], pB); kB = fmaf(K[j].y, H[4*j+1], kB);
    pA = fmaf(Q[j].z, H[4*j+2], pA); kA = fmaf(K[j].z, H[4*j+2], kA);
    pB = fmaf(Q[j].w, H[4*j+3], pB); kB = fmaf(K[j].w, H[4*j+3], kB);
  }
  // (2) decay half of the H-update — independent of g, runs pre-barrier
  float aH[16];
  #pragma unroll
  for (int j = 0; j < 4; j++) {
    aH[4*j+0] = A[j].x * H[4*j+0];
    aH[4*j+1] = A[j].y * H[4*j+1];
    aH[4*j+2] = A[j].z * H[4*j+2];
    aH[4*j+3] = A[j].w * H[4*j+3];
  }
  // (3) cross-wave exchange (only LDS in the kernel)
  buf[(w << 6) + lane] = make_float2(pA + pB, kA + kB);
  asm volatile("s_waitcnt lgkmcnt(0)\n\ts_barrier" ::: "memory");
  float2 x0 = buf[lane], x1 = buf[64 + lane], x2 = buf[128 + lane], x3 = buf[192 + lane];
  float pred = (x0.x + x1.x) + (x2.x + x3.x);
  float kh   = (x0.y + x1.y) + (x2.y + x3.y);
  // (4) surprise gate
  float d = V - pred;
  float e = wave_reduce_add_f32(d * d);
  float sg = __builtin_amdgcn_rcpf(1.f + __builtin_amdgcn_exp2f(e * -1.4426936f));
  float g = sg * (V - kh);
  // (5) H = aH + w*g; y = q . H_new (partial over this wave's rows)
  float yA = 0.f, yB = 0.f;
  #pragma unroll
  for (int j = 0; j < 4; j++) {
    H[4*j+0] = fmaf(W[j].x, g, aH[4*j+0]); yA = fmaf(Q[j].x, H[4*j+0], yA);
    H[4*j+1] = fmaf(W[j].y, g, aH[4*j+1]); yB = fmaf(Q[j].y, H[4*j+1], yB);
    H[4*j+2] = fmaf(W[j].z, g, aH[4*j+2]); yA = fmaf(Q[j].z, H[4*j+2], yA);
    H[4*j+3] = fmaf(W[j].w, g, aH[4*j+3]); yB = fmaf(Q[j].w, H[4*j+3], yB);
  }
  yb[(size_t)t * 256 + (w << 6) + lane] = yA + yB;
}

__global__ __launch_bounds__(256, 1) void k_scan(const float* __restrict__ proj,
                                                 float* __restrict__ ypart)
{
  __shared__ __align__(16) float2 xch[2][256];
  const int b = blockIdx.x, tid = threadIdx.x;
  const int w = tid >> 6, lane = tid & 63;
  const float* pb = proj + (size_t)b * S_ * PST;
  float* yb = ypart + (size_t)b * S_ * 256;
  float H[16];
  #pragma unroll
  for (int j = 0; j < 16; j++) H[j] = 0.f;
  // 4-slot register pipeline, 3-step lookahead
  float4 sK[4][4], sQ[4][4], sA[4][4], sW[4][4]; float sV[4];
  ld_slot(pb, 0, w, lane, sK[0], sQ[0], sA[0], sW[0], sV[0]);
  ld_slot(pb, 1, w, lane, sK[1], sQ[1], sA[1], sW[1], sV[1]);
  ld_slot(pb, 2, w, lane, sK[2], sQ[2], sA[2], sW[2], sV[2]);
  for (int t = 0; t < S_; t += 4) {
    ld_slot(pb, min(t + 3, S_ - 1), w, lane, sK[3], sQ[3], sA[3], sW[3], sV[3]);
    sstep(t,     xch[0], yb, H, sK[0], sQ[0], sA[0], sW[0], sV[0], w, lane);
    ld_slot(pb, min(t + 4, S_ - 1), w, lane, sK[0], sQ[0], sA[0], sW[0], sV[0]);
    sstep(t + 1, xch[1], yb, H, sK[1], sQ[1], sA[1], sW[1], sV[1], w, lane);
    ld_slot(pb, min(t + 5, S_ - 1), w, lane, sK[1], sQ[1], sA[1], sW[1], sV[1]);
    sstep(t + 2, xch[0], yb, H, sK[2], sQ[2], sA[2], sW[2], sV[2], w, lane);
    ld_slot(pb, min(t + 6, S_ - 1), w, lane, sK[2], sQ[2], sA[2], sW[2], sV[2]);
    sstep(t + 3, xch[1], yb, H, sK[3], sQ[3], sA[3], sW[3], sV[3], w, lane);
  }
}

// ---------------------------------------------------------------------------
// Wo transpose (2048x64 -> 64x2048).
// ---------------------------------------------------------------------------
__global__ __launch_bounds__(256) void k_trans(const float* __restrict__ Wo,
                                               float* __restrict__ WoT) {
  int i = blockIdx.x * 256 + threadIdx.x;
  int d = i >> 11;
  int c = i & 2047;
  WoT[i] = Wo[(size_t)c * 64 + d];
}

// ---------------------------------------------------------------------------
// K3: sum y-partials, RMS-norm over 64, * norm_w, then yn @ Wo^T.
// ---------------------------------------------------------------------------
__global__ __launch_bounds__(256) void k_out(const float* __restrict__ ypart,
    const float* __restrict__ norm_w, const float* __restrict__ WoT,
    float* __restrict__ out)
{
  __shared__ __align__(16) float yn[16 * 64];
  const int tid = threadIdx.x;
  const int r0  = blockIdx.x * 16;
  const int c0  = blockIdx.y * 512;
  {
    const int r = tid >> 4;
    const int d = (tid & 15) * 4;
    const float* yp = ypart + (size_t)(r0 + r) * 256;
    float4 y0 = *(const float4*)(yp + d);
    float4 y1 = *(const float4*)(yp + 64 + d);
    float4 y2 = *(const float4*)(yp + 128 + d);
    float4 y3 = *(const float4*)(yp + 192 + d);
    float yx = y0.x + y1.x + y2.x + y3.x;
    float yy = y0.y + y1.y + y2.y + y3.y;
    float yz = y0.z + y1.z + y2.z + y3.z;
    float yw = y0.w + y1.w + y2.w + y3.w;
    float sq = yx * yx + yy * yy + yz * yz + yw * yw;
    sq += __shfl_xor(sq, 1, 64);
    sq += __shfl_xor(sq, 2, 64);
    sq += __shfl_xor(sq, 4, 64);
    sq += __shfl_xor(sq, 8, 64);
    float rms = rsqrtf(sq * (1.f / 64.f) + 1e-6f);
    float4 nw = *(const float4*)(norm_w + d);
    yn[r * 64 + d + 0] = yx * rms * nw.x;
    yn[r * 64 + d + 1] = yy * rms * nw.y;
    yn[r * 64 + d + 2] = yz * rms * nw.z;
    yn[r * 64 + d + 3] = yw * rms * nw.w;
  }
  __syncthreads();
  const int ctq = tid & 127;
  const int rt  = tid >> 7;
  float acc[8][4];
  #pragma unroll
  for (int r = 0; r < 8; r++) { acc[r][0] = 0.f; acc[r][1] = 0.f; acc[r][2] = 0.f; acc[r][3] = 0.f; }
  #pragma unroll 8
  for (int d = 0; d < 64; d++) {
    float4 wv = *(const float4*)(WoT + (size_t)d * 2048 + c0 + ctq * 4);
    #pragma unroll
    for (int r = 0; r < 8; r++) {
      float yv = yn[(rt * 8 + r) * 64 + d];
      acc[r][0] = fmaf(yv, wv.x, acc[r][0]);
      acc[r][1] = fmaf(yv, wv.y, acc[r][1]);
      acc[r][2] = fmaf(yv, wv.z, acc[r][2]);
      acc[r][3] = fmaf(yv, wv.w, acc[r][3]);
    }
  }
  #pragma unroll
  for (int r = 0; r < 8; r++) {
    float4 o; o.x = acc[r][0]; o.y = acc[r][1]; o.z = acc[r][2]; o.w = acc[r][3];
    *(float4*)(out + (size_t)(r0 + rt * 8 + r) * 2048 + c0 + ctq * 4) = o;
  }
}

extern "C" void kernel_launch(void* const* d_in, const int* in_sizes, int n_in,
                              void* d_out, int out_size, void* d_ws, size_t ws_size,
                              hipStream_t stream) {
  const float* x   = (const float*)d_in[0];
  const float* Wk  = (const float*)d_in[1];
  const float* Wv  = (const float*)d_in[2];
  const float* Wq  = (const float*)d_in[3];
  const float* Wa  = (const float*)d_in[4];
  const float* Wab = (const float*)d_in[5];
  const float* lam = (const float*)d_in[6];
  const float* nw  = (const float*)d_in[7];
  const float* Wo  = (const float*)d_in[8];
  float* out = (float*)d_out;

  float* wsf   = (float*)d_ws;
  float* proj  = wsf;                 // 4*2048*320 = 2,621,440 floats
  float* ypart = wsf + 2621440;       // 4*2048*256 = 2,097,152 floats
  float* WoT   = wsf + 4718592;       // 64*2048    =   131,072 floats

  k_trans<<<dim3(512), dim3(256), 0, stream>>>(Wo, WoT);
  k_proj <<<dim3(512), dim3(256), 0, stream>>>(x, Wk, Wv, Wq, Wa, Wab, lam, proj);
  k_scan <<<dim3(4),   dim3(256), 0, stream>>>(proj, ypart);
  k_out  <<<dim3(512, 4), dim3(256), 0, stream>>>(ypart, nw, WoT, out);
}

// Round 6
// 1367.221 us; speedup vs baseline: 1.3975x; 1.2559x over previous
//
#include <hip/hip_runtime.h>
#include <hip/hip_bf16.h>
#include <math.h>

#define S_ 2048
#define DM_ 2048

// Full-wave (64-lane) sum via DPP row_shr/row_bcast, broadcast via readlane.
__device__ __forceinline__ float wave_reduce_add_f32(float x) {
  float t;
  t = __int_as_float(__builtin_amdgcn_update_dpp(0, __float_as_int(x), 0x111, 0xf, 0xf, true)); x += t;
  t = __int_as_float(__builtin_amdgcn_update_dpp(0, __float_as_int(x), 0x112, 0xf, 0xf, true)); x += t;
  t = __int_as_float(__builtin_amdgcn_update_dpp(0, __float_as_int(x), 0x114, 0xf, 0xf, true)); x += t;
  t = __int_as_float(__builtin_amdgcn_update_dpp(0, __float_as_int(x), 0x118, 0xf, 0xf, true)); x += t;
  t = __int_as_float(__builtin_amdgcn_update_dpp(0, __float_as_int(x), 0x142, 0xa, 0xf, true)); x += t;
  t = __int_as_float(__builtin_amdgcn_update_dpp(0, __float_as_int(x), 0x143, 0xc, 0xf, true)); x += t;
  return __int_as_float(__builtin_amdgcn_readlane(__float_as_int(x), 63));
}

// ---------------------------------------------------------------------------
// K1: fused projections. proj row (stride 256): k(l2)@0 | v@64 | q(l2)@128 |
// a@192. Scalar qw[row] = sum_j q_j (1-a_j) k_j stored separately.
// ---------------------------------------------------------------------------
__global__ __launch_bounds__(256) void k_proj(
    const float* __restrict__ x, const float* __restrict__ Wk,
    const float* __restrict__ Wv, const float* __restrict__ Wq,
    const float* __restrict__ Wa, const float* __restrict__ Wab,
    const float* __restrict__ lam, float* __restrict__ proj,
    float* __restrict__ qwArr)
{
  __shared__ __align__(16) float xs[16 * 40];
  __shared__ __align__(16) float ws[32 * 260];
  const int tid = threadIdx.x;
  const int r0  = blockIdx.x * 16;
  const int ct  = tid & 63;
  const int rt  = tid >> 6;
  float acc[4][4];
  #pragma unroll
  for (int r = 0; r < 4; r++) { acc[r][0] = 0.f; acc[r][1] = 0.f; acc[r][2] = 0.f; acc[r][3] = 0.f; }

  const int sg = tid >> 3;
  const int sm = tid & 7;
  const float* wbase[4] = {Wk, Wv, Wq, Wa};

  for (int k0 = 0; k0 < DM_; k0 += 32) {
    if (tid < 128) {
      const int rr = tid >> 3;
      const int ko = (tid & 7) << 2;
      float4 xv = *(const float4*)(x + (size_t)(r0 + rr) * DM_ + k0 + ko);
      *(float4*)(xs + rr * 40 + ko) = xv;
    }
    #pragma unroll
    for (int p = 0; p < 8; p++) {
      const int c = sg + p * 32;
      const float* wb = wbase[p >> 1];
      const int cc = c - (p >> 1) * 64;
      float4 wv = *(const float4*)(wb + (size_t)cc * DM_ + k0 + sm * 4);
      ws[(sm * 4 + 0) * 260 + c] = wv.x;
      ws[(sm * 4 + 1) * 260 + c] = wv.y;
      ws[(sm * 4 + 2) * 260 + c] = wv.z;
      ws[(sm * 4 + 3) * 260 + c] = wv.w;
    }
    __syncthreads();
    #pragma unroll
    for (int kq = 0; kq < 8; kq++) {
      float4 xv[4];
      #pragma unroll
      for (int r = 0; r < 4; r++) xv[r] = *(const float4*)(xs + (rt * 4 + r) * 40 + kq * 4);
      #pragma unroll
      for (int i = 0; i < 4; i++) {
        const int kk = kq * 4 + i;
        float wv0 = ws[kk * 260 + ct];
        float wv1 = ws[kk * 260 + ct + 64];
        float wv2 = ws[kk * 260 + ct + 128];
        float wv3 = ws[kk * 260 + ct + 192];
        #pragma unroll
        for (int r = 0; r < 4; r++) {
          float xr = (i == 0) ? xv[r].x : (i == 1) ? xv[r].y : (i == 2) ? xv[r].z : xv[r].w;
          acc[r][0] = fmaf(xr, wv0, acc[r][0]);
          acc[r][1] = fmaf(xr, wv1, acc[r][1]);
          acc[r][2] = fmaf(xr, wv2, acc[r][2]);
          acc[r][3] = fmaf(xr, wv3, acc[r][3]);
        }
      }
    }
    __syncthreads();
  }
  float lamv = lam[ct];
  float la = logf(1.f / (1.f + expf(-lamv)) + 1e-8f);
  float bv = Wab[ct];
  #pragma unroll
  for (int r = 0; r < 4; r++) {
    float nk = wave_reduce_add_f32(acc[r][0] * acc[r][0]);
    float nq = wave_reduce_add_f32(acc[r][2] * acc[r][2]);
    nk = fmaxf(sqrtf(nk), 1e-12f);
    nq = fmaxf(sqrtf(nq), 1e-12f);
    float pre = acc[r][3] + bv;
    float rr_ = 1.f / (1.f + expf(-pre));
    float al  = expf(8.f * rr_ * la);
    float kn  = acc[r][0] / nk;
    float qn  = acc[r][2] / nq;
    float qw  = wave_reduce_add_f32(qn * (1.f - al) * kn);
    float* pr = proj + (size_t)(r0 + rt * 4 + r) * 256;
    pr[ct]        = kn;
    pr[64 + ct]   = acc[r][1];
    pr[128 + ct]  = qn;
    pr[192 + ct]  = al;
    if (ct == 0) qwArr[r0 + rt * 4 + r] = qw;
  }
}

// ---------------------------------------------------------------------------
// K2: sequential scan. 1 block/batch, 4 waves x 16 H-rows, lane = v-column.
// Input path (cheapest measured): 1 coalesced global dword/thread/step,
// register-held 2 steps, ds_written to a 4-slot LDS ring; k/q/a/v consumed
// as wave-uniform broadcast b128 reads issued one step early (post-barrier).
// Serial chain: dots -> b64 exchange write -> lgkm-only barrier -> 4 b64
// reads -> DPP reduce -> sigmoid -> H update. y = qa.H_old + qw*g (tail-free).
// ---------------------------------------------------------------------------
struct KQA { float4 k[4], q[4], a[4]; float v; };

__device__ __forceinline__ void load_kqa(const float* __restrict__ slot,
                                         int w, int lane, KQA& s) {
  const float4* s4 = (const float4*)slot;
  const int o = w * 4;
  #pragma unroll
  for (int i = 0; i < 4; i++) {
    s.k[i] = s4[o + i];         // k @ floats 0   (wave-uniform broadcast)
    s.q[i] = s4[32 + o + i];    // q @ floats 128
    s.a[i] = s4[48 + o + i];    // a @ floats 192
  }
  s.v = slot[64 + lane];        // v @ floats 64, per-lane
}

__device__ __forceinline__ void sstep(int t, float qws, float* __restrict__ inv,
    float2* __restrict__ xchp, float* __restrict__ yb, const float* __restrict__ pb,
    float H[16], KQA& cur, KQA& nxt, float& pf, int w, int lane, int tid,
    float qwSel)
{
  // phase 0: ring write (data for step t+2), global prefetch (step t+4)
  inv[(((t + 2) & 3) << 8) + tid] = pf;
  pf = pb[(size_t)min(t + 4, S_ - 1) * 256 + tid];
  // phase A: derive w_=(1-a)k, qa=q*a; three dots over H_old
  float4 w4[4], qa4[4];
  #pragma unroll
  for (int j = 0; j < 4; j++) {
    w4[j].x = (1.f - cur.a[j].x) * cur.k[j].x;  qa4[j].x = cur.q[j].x * cur.a[j].x;
    w4[j].y = (1.f - cur.a[j].y) * cur.k[j].y;  qa4[j].y = cur.q[j].y * cur.a[j].y;
    w4[j].z = (1.f - cur.a[j].z) * cur.k[j].z;  qa4[j].z = cur.q[j].z * cur.a[j].z;
    w4[j].w = (1.f - cur.a[j].w) * cur.k[j].w;  qa4[j].w = cur.q[j].w * cur.a[j].w;
  }
  float pA = 0.f, pB = 0.f, kA = 0.f, kB = 0.f, yA = 0.f, yB = 0.f;
  #pragma unroll
  for (int j = 0; j < 4; j++) {
    pA = fmaf(cur.q[j].x, H[4*j+0], pA); kA = fmaf(cur.k[j].x, H[4*j+0], kA); yA = fmaf(qa4[j].x, H[4*j+0], yA);
    pB = fmaf(cur.q[j].y, H[4*j+1], pB); kB = fmaf(cur.k[j].y, H[4*j+1], kB); yB = fmaf(qa4[j].y, H[4*j+1], yB);
    pA = fmaf(cur.q[j].z, H[4*j+2], pA); kA = fmaf(cur.k[j].z, H[4*j+2], kA); yA = fmaf(qa4[j].z, H[4*j+2], yA);
    pB = fmaf(cur.q[j].w, H[4*j+3], pB); kB = fmaf(cur.k[j].w, H[4*j+3], kB); yB = fmaf(qa4[j].w, H[4*j+3], yB);
  }
  // exchange + lgkm-only barrier
  xchp[(w << 6) + lane] = make_float2(pA + pB, kA + kB);
  asm volatile("s_waitcnt lgkmcnt(0)\n\ts_barrier" ::: "memory");
  float2 x0 = xchp[lane], x1 = xchp[64 + lane], x2 = xchp[128 + lane], x3 = xchp[192 + lane];
  // issue next step's input reads (latency hidden behind tail + next phase A)
  load_kqa(inv + (((t + 1) & 3) << 8), w, lane, nxt);
  float pred = (x0.x + x1.x) + (x2.x + x3.x);
  float kh   = (x0.y + x1.y) + (x2.y + x3.y);
  float d = cur.v - pred;
  float e = wave_reduce_add_f32(d * d);
  float sg = __builtin_amdgcn_rcpf(1.f + __builtin_amdgcn_exp2f(e * -1.4426936f));
  float g = sg * (cur.v - kh);
  // y from H_old + qw*g (wave 0 adds the scalar term once)
  yb[(size_t)t * 256 + (w << 6) + lane] = (yA + yB) + qwSel * (qws * g);
  // H = a*H + w_*g
  #pragma unroll
  for (int j = 0; j < 4; j++) {
    H[4*j+0] = fmaf(cur.a[j].x, H[4*j+0], w4[j].x * g);
    H[4*j+1] = fmaf(cur.a[j].y, H[4*j+1], w4[j].y * g);
    H[4*j+2] = fmaf(cur.a[j].z, H[4*j+2], w4[j].z * g);
    H[4*j+3] = fmaf(cur.a[j].w, H[4*j+3], w4[j].w * g);
  }
}

__global__ __launch_bounds__(256, 1) void k_scan(const float* __restrict__ proj,
    const float* __restrict__ qwArr, float* __restrict__ ypart)
{
  __shared__ __align__(16) float inv[4 * 256];     // 4-slot input ring
  __shared__ __align__(16) float2 xch[2][256];     // ping-pong exchange
  const int b = blockIdx.x, tid = threadIdx.x;
  const int w = tid >> 6, lane = tid & 63;
  const float* pb  = proj + (size_t)b * S_ * 256;
  const float* qwb = qwArr + (size_t)b * S_;
  float* yb = ypart + (size_t)b * S_ * 256;
  float H[16];
  #pragma unroll
  for (int j = 0; j < 16; j++) H[j] = 0.f;
  // init: slots 0,1 in LDS; steps 2,3 in registers
  inv[tid]       = pb[tid];
  inv[256 + tid] = pb[256 + tid];
  float pfE = pb[2 * 256 + tid];
  float pfO = pb[3 * 256 + tid];
  __syncthreads();
  const float qwSel = (w == 0) ? 1.f : 0.f;
  KQA curA, curB;
  load_kqa(inv, w, lane, curA);   // step-0 inputs
  for (int t0 = 0; t0 < S_; t0 += 64) {
    float qwv = qwb[t0 + lane];   // 64 qw scalars, one per lane
    for (int tt = 0; tt < 64; tt += 2) {
      float qs0 = __int_as_float(__builtin_amdgcn_readlane(__float_as_int(qwv), tt));
      float qs1 = __int_as_float(__builtin_amdgcn_readlane(__float_as_int(qwv), tt + 1));
      sstep(t0 + tt,     qs0, inv, xch[0], yb, pb, H, curA, curB, pfE, w, lane, tid, qwSel);
      sstep(t0 + tt + 1, qs1, inv, xch[1], yb, pb, H, curB, curA, pfO, w, lane, tid, qwSel);
    }
  }
}

// ---------------------------------------------------------------------------
// Wo transpose (2048x64 -> 64x2048).
// ---------------------------------------------------------------------------
__global__ __launch_bounds__(256) void k_trans(const float* __restrict__ Wo,
                                               float* __restrict__ WoT) {
  int i = blockIdx.x * 256 + threadIdx.x;
  int d = i >> 11;
  int c = i & 2047;
  WoT[i] = Wo[(size_t)c * 64 + d];
}

// ---------------------------------------------------------------------------
// K3: sum y-partials, RMS-norm over 64, * norm_w, then yn @ Wo^T.
// ---------------------------------------------------------------------------
__global__ __launch_bounds__(256) void k_out(const float* __restrict__ ypart,
    const float* __restrict__ norm_w, const float* __restrict__ WoT,
    float* __restrict__ out)
{
  __shared__ __align__(16) float yn[16 * 64];
  const int tid = threadIdx.x;
  const int r0  = blockIdx.x * 16;
  const int c0  = blockIdx.y * 512;
  {
    const int r = tid >> 4;
    const int d = (tid & 15) * 4;
    const float* yp = ypart + (size_t)(r0 + r) * 256;
    float4 y0 = *(const float4*)(yp + d);
    float4 y1 = *(const float4*)(yp + 64 + d);
    float4 y2 = *(const float4*)(yp + 128 + d);
    float4 y3 = *(const float4*)(yp + 192 + d);
    float yx = y0.x + y1.x + y2.x + y3.x;
    float yy = y0.y + y1.y + y2.y + y3.y;
    float yz = y0.z + y1.z + y2.z + y3.z;
    float yw = y0.w + y1.w + y2.w + y3.w;
    float sq = yx * yx + yy * yy + yz * yz + yw * yw;
    sq += __shfl_xor(sq, 1, 64);
    sq += __shfl_xor(sq, 2, 64);
    sq += __shfl_xor(sq, 4, 64);
    sq += __shfl_xor(sq, 8, 64);
    float rms = rsqrtf(sq * (1.f / 64.f) + 1e-6f);
    float4 nw = *(const float4*)(norm_w + d);
    yn[r * 64 + d + 0] = yx * rms * nw.x;
    yn[r * 64 + d + 1] = yy * rms * nw.y;
    yn[r * 64 + d + 2] = yz * rms * nw.z;
    yn[r * 64 + d + 3] = yw * rms * nw.w;
  }
  __syncthreads();
  const int ctq = tid & 127;
  const int rt  = tid >> 7;
  float acc[8][4];
  #pragma unroll
  for (int r = 0; r < 8; r++) { acc[r][0] = 0.f; acc[r][1] = 0.f; acc[r][2] = 0.f; acc[r][3] = 0.f; }
  #pragma unroll 8
  for (int d = 0; d < 64; d++) {
    float4 wv = *(const float4*)(WoT + (size_t)d * 2048 + c0 + ctq * 4);
    #pragma unroll
    for (int r = 0; r < 8; r++) {
      float yv = yn[(rt * 8 + r) * 64 + d];
      acc[r][0] = fmaf(yv, wv.x, acc[r][0]);
      acc[r][1] = fmaf(yv, wv.y, acc[r][1]);
      acc[r][2] = fmaf(yv, wv.z, acc[r][2]);
      acc[r][3] = fmaf(yv, wv.w, acc[r][3]);
    }
  }
  #pragma unroll
  for (int r = 0; r < 8; r++) {
    float4 o; o.x = acc[r][0]; o.y = acc[r][1]; o.z = acc[r][2]; o.w = acc[r][3];
    *(float4*)(out + (size_t)(r0 + rt * 8 + r) * 2048 + c0 + ctq * 4) = o;
  }
}

extern "C" void kernel_launch(void* const* d_in, const int* in_sizes, int n_in,
                              void* d_out, int out_size, void* d_ws, size_t ws_size,
                              hipStream_t stream) {
  const float* x   = (const float*)d_in[0];
  const float* Wk  = (const float*)d_in[1];
  const float* Wv  = (const float*)d_in[2];
  const float* Wq  = (const float*)d_in[3];
  const float* Wa  = (const float*)d_in[4];
  const float* Wab = (const float*)d_in[5];
  const float* lam = (const float*)d_in[6];
  const float* nw  = (const float*)d_in[7];
  const float* Wo  = (const float*)d_in[8];
  float* out = (float*)d_out;

  float* wsf   = (float*)d_ws;
  float* proj  = wsf;                 // 4*2048*256 = 2,097,152 floats
  float* ypart = wsf + 2097152;       // 4*2048*256 = 2,097,152 floats
  float* WoT   = wsf + 4194304;       // 64*2048    =   131,072 floats
  float* qwArr = wsf + 4325376;       // 4*2048     =     8,192 floats

  k_trans<<<dim3(512), dim3(256), 0, stream>>>(Wo, WoT);
  k_proj <<<dim3(512), dim3(256), 0, stream>>>(x, Wk, Wv, Wq, Wa, Wab, lam, proj, qwArr);
  k_scan <<<dim3(4),   dim3(256), 0, stream>>>(proj, qwArr, ypart);
  k_out  <<<dim3(512, 4), dim3(256), 0, stream>>>(ypart, nw, WoT, out);
}